// Round 2
// baseline (343.333 us; speedup 1.0000x reference)
//
#include <hip/hip_runtime.h>

#define DIM   4096
#define KVDIM 1024   // n_kv_heads * head_dim
#define NB    8      // batch
#define TOTAL 16384

typedef float f4 __attribute__((ext_vector_type(4)));   // clang vector: valid for nontemporal builtins

// ---------------------------------------------------------------------------
// x[b*KVDIM + j] = dot(emb[b,:], W_up[j,:])  -- one wave per (j,b), unrolled x16
// (unchanged from previous best: reads inputs only, ~10 us)
// ---------------------------------------------------------------------------
__global__ __launch_bounds__(256)
void k_up(const float* __restrict__ emb, const float* __restrict__ wup,
          float* __restrict__ x) {
    int wid  = blockIdx.x * 4 + (threadIdx.x >> 6);
    int lane = threadIdx.x & 63;
    int j = wid >> 3;      // 0..1023 (8 consecutive waves share one W_up row)
    int b = wid & 7;
    const float4* e = (const float4*)(emb + b * DIM);
    const float4* w = (const float4*)(wup + (long)j * DIM);
    float acc = 0.f;
    #pragma unroll
    for (int ii = 0; ii < 16; ii++) {
        int it = ii * 64 + lane;
        float4 ev = e[it], wv = w[it];
        acc += ev.x * wv.x + ev.y * wv.y + ev.z * wv.z + ev.w * wv.w;
    }
    #pragma unroll
    for (int off = 32; off; off >>= 1) acc += __shfl_down(acc, off, 64);
    if (lane == 0) x[b * KVDIM + j] = acc;
}

// ---------------------------------------------------------------------------
// k_down: y[b*DIM + o] = dot(val[b,:], W_down[o,:])
//         val[b,k] = x[b, (k>>9)*128 + (k&127)]
// x (32 KB) staged into LDS ONCE per block; 4 columns per block (1 per wave),
// so x global traffic drops 4096x32KB=537MB -> 1024x32KB=34MB.
// LDS gather is conflict-free: within a half-wave reads are 16B-contiguous,
// and lanes l / l+32 read the SAME address (repeat-interleave) = broadcast.
// ---------------------------------------------------------------------------
__global__ __launch_bounds__(256)
void k_down(const float* __restrict__ x, const float* __restrict__ wdn,
            float* __restrict__ y) {
    __shared__ float xs[NB * KVDIM];            // 32 KB
    // cooperative stage: 2048 float4, 8 per thread, coalesced
    const float4* xg = (const float4*)x;
    float4* xs4 = (float4*)xs;
    #pragma unroll
    for (int i = 0; i < 8; i++)
        xs4[threadIdx.x + i * 256] = xg[threadIdx.x + i * 256];
    __syncthreads();

    int wv   = threadIdx.x >> 6;                // wave id -> column
    int lane = threadIdx.x & 63;
    int o    = blockIdx.x * 4 + wv;             // 0..4095
    const float4* w = (const float4*)(wdn + (long)o * DIM);

    float acc[NB];
    #pragma unroll
    for (int b = 0; b < NB; b++) acc[b] = 0.f;

    #pragma unroll
    for (int ii = 0; ii < 16; ii++) {
        int it = ii * 64 + lane;                // float4 index, covers K=4096
        float4 wvv = w[it];                     // streamed W_down (read once)
        int k0  = it * 4;
        int kvi = ((k0 >> 9) << 7) + (k0 & 127);
        #pragma unroll
        for (int b = 0; b < NB; b++) {
            const float4 xv = *(const float4*)(xs + b * KVDIM + kvi);
            acc[b] += xv.x * wvv.x + xv.y * wvv.y + xv.z * wvv.z + xv.w * wvv.w;
        }
    }
    #pragma unroll
    for (int b = 0; b < NB; b++) {
        #pragma unroll
        for (int off = 32; off; off >>= 1) acc[b] += __shfl_down(acc[b], off, 64);
    }
    if (lane == 0) {
        #pragma unroll
        for (int b = 0; b < NB; b++) y[b * DIM + o] = acc[b];
    }
}

// ---------------------------------------------------------------------------
// k_bcast: out[row,:] = y[seq_id(row),:]
// block = (16-row window) x (1024-float column window). Each thread holds its
// float4 of the y row in a REGISTER and reloads only when the sequence id
// changes inside the window (y read traffic 268MB -> ~16MB). Stores are
// nontemporal: pure 268MB write stream, no L2 write-allocate pollution.
// grid = (TOTAL/16) * (DIM/1024) = 1024 * 4 = 4096 blocks.
// ---------------------------------------------------------------------------
#define BC_ROWS 16
__global__ __launch_bounds__(256)
void k_bcast(const float* __restrict__ y, const int* __restrict__ seqlen,
             float* __restrict__ out) {
    int rw  = blockIdx.x >> 2;                  // row window 0..1023
    int cw  = blockIdx.x & 3;                   // col window 0..3
    int col = cw * 1024 + threadIdx.x * 4;

    int c0 = seqlen[0];
    int c1 = c0 + seqlen[1];
    int c2 = c1 + seqlen[2];
    int c3 = c2 + seqlen[3];
    int c4 = c3 + seqlen[4];
    int c5 = c4 + seqlen[5];
    int c6 = c5 + seqlen[6];

    int row0 = rw * BC_ROWS;
    int s_cur = -1;
    f4 yv = (f4)(0.f);
    #pragma unroll
    for (int r = 0; r < BC_ROWS; r++) {
        int row = row0 + r;
        int s = (row >= c0) + (row >= c1) + (row >= c2) + (row >= c3)
              + (row >= c4) + (row >= c5) + (row >= c6);
        if (s != s_cur) {                       // uniform branch, rare
            yv = *(const f4*)(y + s * DIM + col);
            s_cur = s;
        }
        __builtin_nontemporal_store(yv, (f4*)(out + (long)row * DIM + col));
    }
}

extern "C" void kernel_launch(void* const* d_in, const int* in_sizes, int n_in,
                              void* d_out, int out_size, void* d_ws, size_t ws_size,
                              hipStream_t stream) {
    const float* emb = (const float*)d_in[0];
    const float* wup = (const float*)d_in[1];
    const float* wdn = (const float*)d_in[2];
    const int* seqlen = (const int*)d_in[3];

    float* x = (float*)d_ws;           // 8*1024 fp32 = 32 KB
    float* y = x + NB * KVDIM;         // 8*4096 fp32 = 128 KB

    k_up   <<<NB * KVDIM / 4,            256, 0, stream>>>(emb, wup, x);
    k_down <<<DIM / 4,                   256, 0, stream>>>(x, wdn, y);
    k_bcast<<<(TOTAL / BC_ROWS) * 4,     256, 0, stream>>>(y, seqlen, (float*)d_out);
}